// Round 18
// baseline (42.579 us; speedup 1.0000x reference)
//
#include <hip/hip_runtime.h>
#include <hip/hip_bf16.h>

#define BB 16
#define NN 128
#define DD 128

typedef __attribute__((ext_vector_type(8))) short s8v;   // 8 bf16 (4 VGPRs)
typedef __attribute__((ext_vector_type(4))) float f4v;   // MFMA C/D

__device__ __forceinline__ unsigned short f2bf(float f) {
    __hip_bfloat16 b = __float2bfloat16(f);
    return *reinterpret_cast<unsigned short*>(&b);
}

// front: ROLE-ORDERED fusion (R17-proven skeleton).
//   bid 0..47    : prep G-GEMM (chunked 16-KB staging)
//   bid 48       : WuA copy + bmWu
//   bid 49..56   : h -> bf16 cast
//   bid 57..312  : ah + deg
//   bid 313..1336: es, J-PAIR DENSE read — one 64-lane wave covers the
//                  adjacent 512-B fragments of j and j+1 for one i
//                  (1 KB contiguous per wave-load, R8-proven ~6 TB/s regime);
//                  4 waves stride the 128 i's. Dense = no branches, no
//                  compaction; zeros handled by the FMA.
__global__ __launch_bounds__(256) void front_kernel(
    const float* __restrict__ h, const float* __restrict__ adj,
    const float* __restrict__ e, const float* __restrict__ Wm,
    const float* __restrict__ bm, const float* __restrict__ Wu,
    unsigned short* __restrict__ BT, float* __restrict__ bmWu,
    unsigned short* __restrict__ hbf, unsigned short* __restrict__ esbf,
    unsigned short* __restrict__ AHbf, float* __restrict__ deg) {
    const int bid = blockIdx.x, t = threadIdx.x;

    __shared__ float sm_big[4096];      // 16 KB: prep chunk / ah adj_s / es {adj2,red}

    if (bid < 48) {
        // -------- prep: G_m[k][d] = sum_kk Wm[kk,off+d]*Wu[k,128+kk] --------
        float* chunk = sm_big;                        // [32][128] = 16 KB
        const int m = bid >> 4, dc = bid & 15;
        const int off   = (m == 0) ? 0   : (m == 1) ? 256 : 128;
        const int rbase = (m == 0) ? 128 : (m == 1) ? 256 : 384;
        const int k = t & 127, dh = t >> 7;
        const int d0 = dc * 8 + dh * 4;
        float a0 = 0, a1 = 0, a2 = 0, a3 = 0;
        for (int c = 0; c < 4; ++c) {
            for (int x = t; x < 32 * 128; x += 256) {
                const int kk = x >> 7, kcol = x & 127;
                chunk[kk * 128 + kcol] = Wu[kcol * 256 + 128 + c * 32 + kk];
            }
            __syncthreads();
            #pragma unroll 8
            for (int kk = 0; kk < 32; ++kk) {
                const float wu = chunk[kk * 128 + k];
                const float* wmp = Wm + (c * 32 + kk) * 384 + off + d0;
                a0 += wmp[0] * wu; a1 += wmp[1] * wu;
                a2 += wmp[2] * wu; a3 += wmp[3] * wu;
            }
            __syncthreads();
        }
        unsigned short* bp = BT + (size_t)k * 512 + rbase + d0;
        bp[0] = f2bf(a0); bp[1] = f2bf(a1); bp[2] = f2bf(a2); bp[3] = f2bf(a3);
    } else if (bid == 48) {
        for (int p = 0; p < 64; ++p) {                // WuA^T copy, BT rows 0-127
            const int x = p * 256 + t, k = x >> 7, d = x & 127;
            BT[(size_t)k * 512 + d] = f2bf(Wu[k * 256 + d]);
        }
        if (t < 128) {
            float s = 0.f;
            for (int kk = 0; kk < 128; ++kk) s += bm[kk] * Wu[t * 256 + 128 + kk];
            bmWu[t] = s;
        }
    } else if (bid < 57) {
        // -------- h -> bf16 cast --------
        const int bi = bid - 49;
        const float4* h4 = (const float4*)h;
        uint2* hb2 = (uint2*)hbf;
        for (int p = 0; p < 32; ++p) {
            const int i4 = bi * 8192 + p * 256 + t;
            const float4 v = h4[i4];
            hb2[i4] = make_uint2((unsigned)f2bf(v.x) | ((unsigned)f2bf(v.y) << 16),
                                 (unsigned)f2bf(v.z) | ((unsigned)f2bf(v.w) << 16));
        }
    } else if (bid < 313) {
        // -------- ah role: AH[b,j,k] = sum_i adj[i,j]*h[b,i,k]; deg --------
        const int b2 = bid - 57;
        const int b = b2 >> 4, jbase = (b2 & 15) * 8;
        float (*adj_s)[NN] = (float (*)[NN])sm_big;   // [8][128] = 4 KB
        for (int x = t; x < 8 * NN; x += 256) {
            const int i = x >> 3, j2 = x & 7;
            adj_s[j2][i] = adj[(size_t)(b * NN + i) * NN + jbase + j2];
        }
        __syncthreads();
        {   // deg for the 8 j's: 8 groups of 32 lanes
            const int jj = t >> 5, l = t & 31;
            float s = adj_s[jj][l] + adj_s[jj][l + 32] + adj_s[jj][l + 64] + adj_s[jj][l + 96];
            #pragma unroll
            for (int off = 16; off; off >>= 1) s += __shfl_xor(s, off);
            if (l == 0) deg[b * NN + jbase + jj] = s;
        }
        const int k = t & 127, jh = t >> 7;           // j = jh, jh+2, jh+4, jh+6
        float a0 = 0.f, a1 = 0.f, a2 = 0.f, a3 = 0.f;
        const float* __restrict__ hp = h + (size_t)b * NN * DD + k;
        #pragma unroll 8
        for (int m = 0; m < 32; ++m) {
            const float4 aA = *(const float4*)&adj_s[jh][4 * m];
            const float4 aB = *(const float4*)&adj_s[jh + 2][4 * m];
            const float4 aC = *(const float4*)&adj_s[jh + 4][4 * m];
            const float4 aD = *(const float4*)&adj_s[jh + 6][4 * m];
            const float h0 = hp[(size_t)(4 * m + 0) * DD];
            const float h1 = hp[(size_t)(4 * m + 1) * DD];
            const float h2 = hp[(size_t)(4 * m + 2) * DD];
            const float h3 = hp[(size_t)(4 * m + 3) * DD];
            a0 += aA.x * h0 + aA.y * h1 + aA.z * h2 + aA.w * h3;
            a1 += aB.x * h0 + aB.y * h1 + aB.z * h2 + aB.w * h3;
            a2 += aC.x * h0 + aC.y * h1 + aC.z * h2 + aC.w * h3;
            a3 += aD.x * h0 + aD.y * h1 + aD.z * h2 + aD.w * h3;
        }
        AHbf[(size_t)(b * NN + jbase + jh) * DD + k]     = f2bf(a0);
        AHbf[(size_t)(b * NN + jbase + jh + 2) * DD + k] = f2bf(a1);
        AHbf[(size_t)(b * NN + jbase + jh + 4) * DD + k] = f2bf(a2);
        AHbf[(size_t)(b * NN + jbase + jh + 6) * DD + k] = f2bf(a3);
    } else {
        // -------- es role: j-pair dense, 1-KB wave-contiguous loads --------
        const int bjp = bid - 313;                    // 0..1023
        const int b = bjp >> 6, j0 = (bjp & 63) * 2;
        float  (*adj2)[2] = (float (*)[2])sm_big;     // [128][2] = 1 KB
        float4* red2 = (float4*)(sm_big + 256);       // [4][64] float4 = 4 KB
        if (t < 256) {
            const int i = t >> 1, jc = t & 1;
            adj2[i][jc] = adj[(size_t)(b * NN + i) * NN + j0 + jc];
        }
        __syncthreads();
        const int w = t >> 6, l = t & 63;
        const int jsel = l >> 5, d4 = l & 31;
        const float4* __restrict__ ep =
            (const float4*)e + ((size_t)(b * NN) * NN + j0 + jsel) * 32 + d4;
        f4v acc = {0.f, 0.f, 0.f, 0.f};
        #pragma unroll 4
        for (int m = 0; m < 32; ++m) {
            const int i = 4 * m + w;                  // wave w: i = w, w+4, ...
            const float a = adj2[i][jsel];
            const float4 v = ep[(size_t)i * (NN * 32)];
            acc.x += a * v.x; acc.y += a * v.y;
            acc.z += a * v.z; acc.w += a * v.w;
        }
        red2[w * 64 + l] = make_float4(acc.x, acc.y, acc.z, acc.w);
        __syncthreads();
        if (t < 64) {
            const float4 s0 = red2[t], s1 = red2[64 + t];
            const float4 s2 = red2[128 + t], s3 = red2[192 + t];
            const float sx = s0.x + s1.x + s2.x + s3.x;
            const float sy = s0.y + s1.y + s2.y + s3.y;
            const float sz = s0.z + s1.z + s2.z + s3.z;
            const float sw = s0.w + s1.w + s2.w + s3.w;
            ((uint2*)esbf)[((size_t)(b * NN + j0 + (t >> 5))) * 32 + (t & 31)] =
                make_uint2((unsigned)f2bf(sx) | ((unsigned)f2bf(sy) << 16),
                           (unsigned)f2bf(sz) | ((unsigned)f2bf(sw) << 16));
        }
    }
}

// out: MFMA GEMM (R10-proven). acc1 = [h|AH|es]·[WuAT;G1T;G3T]; acc2 = h·G2T.
// out = acc1 + deg*acc2 + deg*bmWu + bu.
__global__ __launch_bounds__(256) void out_kernel(
    const unsigned short* __restrict__ hbf, const unsigned short* __restrict__ AHbf,
    const unsigned short* __restrict__ esbf, const unsigned short* __restrict__ BT,
    const float* __restrict__ deg, const float* __restrict__ bmWu,
    const float* __restrict__ bu, float* __restrict__ out) {
    const int rt = blockIdx.x >> 2, ct = blockIdx.x & 3;
    const int t = threadIdx.x;
    const int l = t & 63, wid = t >> 6, mw = wid >> 1, nw = wid & 1;
    __shared__ unsigned short A_s[32][72], B_s[32][72], B2_s[32][72];
    f4v acc1 = {0.f, 0.f, 0.f, 0.f};
    f4v acc2 = {0.f, 0.f, 0.f, 0.f};
    const int rA = t >> 3, cb = t & 7;
    const int arow = mw * 16 + (l & 15);
    const int brow = nw * 16 + (l & 15);
    const int lg = l >> 4;
    for (int c = 0; c < 6; ++c) {
        __syncthreads();
        const unsigned short* src = (c < 2) ? hbf : (c < 4) ? AHbf : esbf;
        const int col0 = (c & 1) * 64;
        const int rowg = rt * 32 + rA;
        *(s8v*)&A_s[rA][cb * 8] = *(const s8v*)&src[(size_t)rowg * 128 + col0 + cb * 8];
        *(s8v*)&B_s[rA][cb * 8] =
            *(const s8v*)&BT[(size_t)(ct * 32 + rA) * 512 + c * 64 + cb * 8];
        if (c < 2)
            *(s8v*)&B2_s[rA][cb * 8] =
                *(const s8v*)&BT[(size_t)(ct * 32 + rA) * 512 + 384 + c * 64 + cb * 8];
        __syncthreads();
        #pragma unroll
        for (int kit = 0; kit < 2; ++kit) {
            const s8v a  = *(const s8v*)&A_s[arow][kit * 32 + lg * 8];
            const s8v bb = *(const s8v*)&B_s[brow][kit * 32 + lg * 8];
            acc1 = __builtin_amdgcn_mfma_f32_16x16x32_bf16(a, bb, acc1, 0, 0, 0);
            if (c < 2) {
                const s8v b2 = *(const s8v*)&B2_s[brow][kit * 32 + lg * 8];
                acc2 = __builtin_amdgcn_mfma_f32_16x16x32_bf16(a, b2, acc2, 0, 0, 0);
            }
        }
    }
    const int colk = ct * 32 + nw * 16 + (l & 15);
    const float bmv = bmWu[colk], buv = bu[colk];
    #pragma unroll
    for (int r = 0; r < 4; ++r) {
        const int rowg = rt * 32 + mw * 16 + (l >> 4) * 4 + r;
        const float dg = deg[rowg];
        out[(size_t)rowg * 128 + colk] = acc1[r] + dg * acc2[r] + dg * bmv + buv;
    }
}

extern "C" void kernel_launch(void* const* d_in, const int* in_sizes, int n_in,
                              void* d_out, int out_size, void* d_ws, size_t ws_size,
                              hipStream_t stream) {
    const float* h   = (const float*)d_in[0];
    const float* adj = (const float*)d_in[1];
    const float* e   = (const float*)d_in[2];
    const float* Wm  = (const float*)d_in[3];
    const float* bm  = (const float*)d_in[4];
    const float* Wu  = (const float*)d_in[5];
    const float* bu  = (const float*)d_in[6];
    float* out = (float*)d_out;

    float* ws = (float*)d_ws;
    unsigned short* BT   = (unsigned short*)ws;             // 128x512 bf16
    float*          bmWu = ws + 32768;                      // 128 f32
    float*          deg  = ws + 32896;                      // 2048 f32
    unsigned short* hbf  = (unsigned short*)(ws + 34944);   // 2048x128 bf16
    unsigned short* AHbf = (unsigned short*)(ws + 166016);  // 2048x128 bf16
    unsigned short* esbf = (unsigned short*)(ws + 297088);  // 2048x128 bf16

    front_kernel<<<313 + 1024, 256, 0, stream>>>(h, adj, e, Wm, bm, Wu,
                                                 BT, bmWu, hbf, esbf, AHbf, deg);
    out_kernel<<<256, 256, 0, stream>>>(hbf, AHbf, esbf, BT, deg, bmWu, bu, out);
}

// Round 19
// 34.169 us; speedup vs baseline: 1.2461x; 1.2461x over previous
//
#include <hip/hip_runtime.h>
#include <hip/hip_bf16.h>

#define BB 16
#define NN 128
#define DD 128

typedef __attribute__((ext_vector_type(8))) short s8v;   // 8 bf16 (4 VGPRs)
typedef __attribute__((ext_vector_type(4))) float f4v;   // MFMA C/D

__device__ __forceinline__ unsigned short f2bf(float f) {
    __hip_bfloat16 b = __float2bfloat16(f);
    return *reinterpret_cast<unsigned short*>(&b);
}

// front: ROLE-ORDERED fusion (R17-proven skeleton).
//   bid 0..47    : prep G-GEMM (chunked 16-KB staging)
//   bid 48       : WuA copy + bmWu
//   bid 49..56   : h -> bf16 cast
//   bid 57..312  : ah + deg
//   bid 313..2360: es — compacted branch-free gather, 8-DEEP load batching
//                  (list padded to x64; dummies index i=0 -> L1-resident).
__global__ __launch_bounds__(256) void front_kernel(
    const float* __restrict__ h, const float* __restrict__ adj,
    const float* __restrict__ e, const float* __restrict__ Wm,
    const float* __restrict__ bm, const float* __restrict__ Wu,
    unsigned short* __restrict__ BT, float* __restrict__ bmWu,
    unsigned short* __restrict__ hbf, unsigned short* __restrict__ esbf,
    unsigned short* __restrict__ AHbf, float* __restrict__ deg) {
    const int bid = blockIdx.x, t = threadIdx.x;

    __shared__ float sm_big[4096];      // 16 KB: prep chunk / ah adj_s / es red
    __shared__ float sm_adj[NN];
    __shared__ int   sm_idx[NN];
    __shared__ float sm_av[NN];
    __shared__ int   sm_cnt;

    if (bid < 48) {
        // -------- prep: G_m[k][d] = sum_kk Wm[kk,off+d]*Wu[k,128+kk] --------
        float* chunk = sm_big;                        // [32][128] = 16 KB
        const int m = bid >> 4, dc = bid & 15;
        const int off   = (m == 0) ? 0   : (m == 1) ? 256 : 128;
        const int rbase = (m == 0) ? 128 : (m == 1) ? 256 : 384;
        const int k = t & 127, dh = t >> 7;
        const int d0 = dc * 8 + dh * 4;
        float a0 = 0, a1 = 0, a2 = 0, a3 = 0;
        for (int c = 0; c < 4; ++c) {
            for (int x = t; x < 32 * 128; x += 256) {
                const int kk = x >> 7, kcol = x & 127;
                chunk[kk * 128 + kcol] = Wu[kcol * 256 + 128 + c * 32 + kk];
            }
            __syncthreads();
            #pragma unroll 8
            for (int kk = 0; kk < 32; ++kk) {
                const float wu = chunk[kk * 128 + k];
                const float* wmp = Wm + (c * 32 + kk) * 384 + off + d0;
                a0 += wmp[0] * wu; a1 += wmp[1] * wu;
                a2 += wmp[2] * wu; a3 += wmp[3] * wu;
            }
            __syncthreads();
        }
        unsigned short* bp = BT + (size_t)k * 512 + rbase + d0;
        bp[0] = f2bf(a0); bp[1] = f2bf(a1); bp[2] = f2bf(a2); bp[3] = f2bf(a3);
    } else if (bid == 48) {
        for (int p = 0; p < 64; ++p) {                // WuA^T copy, BT rows 0-127
            const int x = p * 256 + t, k = x >> 7, d = x & 127;
            BT[(size_t)k * 512 + d] = f2bf(Wu[k * 256 + d]);
        }
        if (t < 128) {
            float s = 0.f;
            for (int kk = 0; kk < 128; ++kk) s += bm[kk] * Wu[t * 256 + 128 + kk];
            bmWu[t] = s;
        }
    } else if (bid < 57) {
        // -------- h -> bf16 cast --------
        const int bi = bid - 49;
        const float4* h4 = (const float4*)h;
        uint2* hb2 = (uint2*)hbf;
        for (int p = 0; p < 32; ++p) {
            const int i4 = bi * 8192 + p * 256 + t;
            const float4 v = h4[i4];
            hb2[i4] = make_uint2((unsigned)f2bf(v.x) | ((unsigned)f2bf(v.y) << 16),
                                 (unsigned)f2bf(v.z) | ((unsigned)f2bf(v.w) << 16));
        }
    } else if (bid < 313) {
        // -------- ah role: AH[b,j,k] = sum_i adj[i,j]*h[b,i,k]; deg --------
        const int b2 = bid - 57;
        const int b = b2 >> 4, jbase = (b2 & 15) * 8;
        float (*adj_s)[NN] = (float (*)[NN])sm_big;   // [8][128] = 4 KB
        for (int x = t; x < 8 * NN; x += 256) {
            const int i = x >> 3, j2 = x & 7;
            adj_s[j2][i] = adj[(size_t)(b * NN + i) * NN + jbase + j2];
        }
        __syncthreads();
        {   // deg for the 8 j's: 8 groups of 32 lanes
            const int jj = t >> 5, l = t & 31;
            float s = adj_s[jj][l] + adj_s[jj][l + 32] + adj_s[jj][l + 64] + adj_s[jj][l + 96];
            #pragma unroll
            for (int off = 16; off; off >>= 1) s += __shfl_xor(s, off);
            if (l == 0) deg[b * NN + jbase + jj] = s;
        }
        const int k = t & 127, jh = t >> 7;           // j = jh, jh+2, jh+4, jh+6
        float a0 = 0.f, a1 = 0.f, a2 = 0.f, a3 = 0.f;
        const float* __restrict__ hp = h + (size_t)b * NN * DD + k;
        #pragma unroll 8
        for (int m = 0; m < 32; ++m) {
            const float4 aA = *(const float4*)&adj_s[jh][4 * m];
            const float4 aB = *(const float4*)&adj_s[jh + 2][4 * m];
            const float4 aC = *(const float4*)&adj_s[jh + 4][4 * m];
            const float4 aD = *(const float4*)&adj_s[jh + 6][4 * m];
            const float h0 = hp[(size_t)(4 * m + 0) * DD];
            const float h1 = hp[(size_t)(4 * m + 1) * DD];
            const float h2 = hp[(size_t)(4 * m + 2) * DD];
            const float h3 = hp[(size_t)(4 * m + 3) * DD];
            a0 += aA.x * h0 + aA.y * h1 + aA.z * h2 + aA.w * h3;
            a1 += aB.x * h0 + aB.y * h1 + aB.z * h2 + aB.w * h3;
            a2 += aC.x * h0 + aC.y * h1 + aC.z * h2 + aC.w * h3;
            a3 += aD.x * h0 + aD.y * h1 + aD.z * h2 + aD.w * h3;
        }
        AHbf[(size_t)(b * NN + jbase + jh) * DD + k]     = f2bf(a0);
        AHbf[(size_t)(b * NN + jbase + jh + 2) * DD + k] = f2bf(a1);
        AHbf[(size_t)(b * NN + jbase + jh + 4) * DD + k] = f2bf(a2);
        AHbf[(size_t)(b * NN + jbase + jh + 6) * DD + k] = f2bf(a3);
    } else {
        // -------- es role: compacted gather, 8-deep batched loads --------
        const int bj = bid - 313;
        const int b = bj >> 7, j = bj & 127;
        float4 (*red)[32] = (float4 (*)[32])sm_big;   // 4 KB of sm_big
        if (t < NN) sm_adj[t] = adj[(size_t)(b * NN + t) * NN + j];
        __syncthreads();
        if (t < 64) {                                 // wave 0: ballot compaction
            const float a0 = sm_adj[t], a1 = sm_adj[t + 64];
            const unsigned long long m0 = __ballot(a0 != 0.0f);
            const unsigned long long m1 = __ballot(a1 != 0.0f);
            const int c0 = __popcll(m0);
            const unsigned long long below = (t == 0) ? 0ull : ((1ull << t) - 1ull);
            const int p0 = __popcll(m0 & below);
            const int p1 = c0 + __popcll(m1 & below);
            if (a0 != 0.0f) { sm_idx[p0] = t;      sm_av[p0] = a0; }
            if (a1 != 0.0f) { sm_idx[p1] = t + 64; sm_av[p1] = a1; }
            const int cnt = c0 + __popcll(m1);
            const int cntP = (cnt + 63) & ~63;        // pad to multiple of 64
            for (int x = cnt + t; x < cntP; x += 64) { sm_idx[x] = 0; sm_av[x] = 0.f; }
            if (t == 0) sm_cnt = cntP;
        }
        __syncthreads();
        const int cnt = sm_cnt;
        const int d4 = t & 31, g = t >> 5;            // 8 groups of 32 lanes
        const float4* __restrict__ ep =
            (const float4*)e + ((size_t)(b * NN) * NN + j) * 32 + d4;
        f4v acc = {0.f, 0.f, 0.f, 0.f};
        for (int base = 0; base < cnt; base += 64) {
            const int n = base + g;
            const int iA = sm_idx[n];      const float aA = sm_av[n];
            const int iB = sm_idx[n + 8];  const float aB = sm_av[n + 8];
            const int iC = sm_idx[n + 16]; const float aC = sm_av[n + 16];
            const int iD = sm_idx[n + 24]; const float aD = sm_av[n + 24];
            const int iE = sm_idx[n + 32]; const float aE = sm_av[n + 32];
            const int iF = sm_idx[n + 40]; const float aF = sm_av[n + 40];
            const int iG = sm_idx[n + 48]; const float aG = sm_av[n + 48];
            const int iH = sm_idx[n + 56]; const float aH = sm_av[n + 56];
            const float4 vA = ep[(size_t)iA * (NN * 32)];
            const float4 vB = ep[(size_t)iB * (NN * 32)];
            const float4 vC = ep[(size_t)iC * (NN * 32)];
            const float4 vD = ep[(size_t)iD * (NN * 32)];
            const float4 vE = ep[(size_t)iE * (NN * 32)];
            const float4 vF = ep[(size_t)iF * (NN * 32)];
            const float4 vG = ep[(size_t)iG * (NN * 32)];
            const float4 vH = ep[(size_t)iH * (NN * 32)];
            acc.x += aA * vA.x + aB * vB.x + aC * vC.x + aD * vD.x
                   + aE * vE.x + aF * vF.x + aG * vG.x + aH * vH.x;
            acc.y += aA * vA.y + aB * vB.y + aC * vC.y + aD * vD.y
                   + aE * vE.y + aF * vF.y + aG * vG.y + aH * vH.y;
            acc.z += aA * vA.z + aB * vB.z + aC * vC.z + aD * vD.z
                   + aE * vE.z + aF * vF.z + aG * vG.z + aH * vH.z;
            acc.w += aA * vA.w + aB * vB.w + aC * vC.w + aD * vD.w
                   + aE * vE.w + aF * vF.w + aG * vG.w + aH * vH.w;
        }
        red[g][d4] = make_float4(acc.x, acc.y, acc.z, acc.w);
        __syncthreads();
        if (t < 32) {
            float4 s = red[0][t];
            #pragma unroll
            for (int r = 1; r < 8; ++r) {
                const float4 v = red[r][t];
                s.x += v.x; s.y += v.y; s.z += v.z; s.w += v.w;
            }
            ((uint2*)esbf)[(size_t)bj * 32 + t] =
                make_uint2((unsigned)f2bf(s.x) | ((unsigned)f2bf(s.y) << 16),
                           (unsigned)f2bf(s.z) | ((unsigned)f2bf(s.w) << 16));
        }
    }
}

// out: MFMA GEMM (R10-proven). acc1 = [h|AH|es]·[WuAT;G1T;G3T]; acc2 = h·G2T.
// out = acc1 + deg*acc2 + deg*bmWu + bu.
__global__ __launch_bounds__(256) void out_kernel(
    const unsigned short* __restrict__ hbf, const unsigned short* __restrict__ AHbf,
    const unsigned short* __restrict__ esbf, const unsigned short* __restrict__ BT,
    const float* __restrict__ deg, const float* __restrict__ bmWu,
    const float* __restrict__ bu, float* __restrict__ out) {
    const int rt = blockIdx.x >> 2, ct = blockIdx.x & 3;
    const int t = threadIdx.x;
    const int l = t & 63, wid = t >> 6, mw = wid >> 1, nw = wid & 1;
    __shared__ unsigned short A_s[32][72], B_s[32][72], B2_s[32][72];
    f4v acc1 = {0.f, 0.f, 0.f, 0.f};
    f4v acc2 = {0.f, 0.f, 0.f, 0.f};
    const int rA = t >> 3, cb = t & 7;
    const int arow = mw * 16 + (l & 15);
    const int brow = nw * 16 + (l & 15);
    const int lg = l >> 4;
    for (int c = 0; c < 6; ++c) {
        __syncthreads();
        const unsigned short* src = (c < 2) ? hbf : (c < 4) ? AHbf : esbf;
        const int col0 = (c & 1) * 64;
        const int rowg = rt * 32 + rA;
        *(s8v*)&A_s[rA][cb * 8] = *(const s8v*)&src[(size_t)rowg * 128 + col0 + cb * 8];
        *(s8v*)&B_s[rA][cb * 8] =
            *(const s8v*)&BT[(size_t)(ct * 32 + rA) * 512 + c * 64 + cb * 8];
        if (c < 2)
            *(s8v*)&B2_s[rA][cb * 8] =
                *(const s8v*)&BT[(size_t)(ct * 32 + rA) * 512 + 384 + c * 64 + cb * 8];
        __syncthreads();
        #pragma unroll
        for (int kit = 0; kit < 2; ++kit) {
            const s8v a  = *(const s8v*)&A_s[arow][kit * 32 + lg * 8];
            const s8v bb = *(const s8v*)&B_s[brow][kit * 32 + lg * 8];
            acc1 = __builtin_amdgcn_mfma_f32_16x16x32_bf16(a, bb, acc1, 0, 0, 0);
            if (c < 2) {
                const s8v b2 = *(const s8v*)&B2_s[brow][kit * 32 + lg * 8];
                acc2 = __builtin_amdgcn_mfma_f32_16x16x32_bf16(a, b2, acc2, 0, 0, 0);
            }
        }
    }
    const int colk = ct * 32 + nw * 16 + (l & 15);
    const float bmv = bmWu[colk], buv = bu[colk];
    #pragma unroll
    for (int r = 0; r < 4; ++r) {
        const int rowg = rt * 32 + mw * 16 + (l >> 4) * 4 + r;
        const float dg = deg[rowg];
        out[(size_t)rowg * 128 + colk] = acc1[r] + dg * acc2[r] + dg * bmv + buv;
    }
}

extern "C" void kernel_launch(void* const* d_in, const int* in_sizes, int n_in,
                              void* d_out, int out_size, void* d_ws, size_t ws_size,
                              hipStream_t stream) {
    const float* h   = (const float*)d_in[0];
    const float* adj = (const float*)d_in[1];
    const float* e   = (const float*)d_in[2];
    const float* Wm  = (const float*)d_in[3];
    const float* bm  = (const float*)d_in[4];
    const float* Wu  = (const float*)d_in[5];
    const float* bu  = (const float*)d_in[6];
    float* out = (float*)d_out;

    float* ws = (float*)d_ws;
    unsigned short* BT   = (unsigned short*)ws;             // 128x512 bf16
    float*          bmWu = ws + 32768;                      // 128 f32
    float*          deg  = ws + 32896;                      // 2048 f32
    unsigned short* hbf  = (unsigned short*)(ws + 34944);   // 2048x128 bf16
    unsigned short* AHbf = (unsigned short*)(ws + 166016);  // 2048x128 bf16
    unsigned short* esbf = (unsigned short*)(ws + 297088);  // 2048x128 bf16

    front_kernel<<<313 + BB * NN, 256, 0, stream>>>(h, adj, e, Wm, bm, Wu,
                                                    BT, bmWu, hbf, esbf, AHbf, deg);
    out_kernel<<<256, 256, 0, stream>>>(hbf, AHbf, esbf, BT, deg, bmWu, bu, out);
}